// Round 6
// baseline (2728.751 us; speedup 1.0000x reference)
//
#include <hip/hip_runtime.h>
#include <hip/hip_bf16.h>

typedef float f32x4 __attribute__((ext_vector_type(4)));
typedef __bf16 bf16x8 __attribute__((ext_vector_type(8)));
typedef unsigned short u16;

#define T_TOK 4096
#define DIMK 2048
#define INTERN 1024
#define NEXP 32
#define NTOPK 6
#define NGRP 8
#define NTOPG 4
#define SINTER 2048
#define MAXPADROWS 29184

// async global->LDS 16B
__device__ __forceinline__ void glds16(const void* g, void* l) {
    auto* gp = (const __attribute__((address_space(1))) int*)(g);
    auto* lp = (__attribute__((address_space(3))) int*)(l);
    __builtin_amdgcn_global_load_lds(gp, lp, 16, 0, 0);
}

// Chunked+swizzled layout for [Rows][K] bf16: row-chunks of 128, k-chunks of 64.
// chunk order: [rowchunk][kchunk] (kchunk fastest). In-chunk (16KB):
//   off = row*64 + ((g ^ (row&7))<<3) + (k&7),  g = (k>>3)&7.
// A wave's ds_read_b128 fragment (16 lanes, rows r..r+15, same granule) then
// spreads across all 8 bank-groups 2-way (free).
__device__ __forceinline__ size_t toff(int row, int k, int K) {
    int g = (k >> 3) & 7;
    return (size_t)(row >> 7) * (size_t)(128 * K) + (size_t)(k >> 6) * 8192 +
           (size_t)((row & 127) * 64 + ((g ^ (row & 7)) << 3) + (k & 7));
}

// ---------------- cast x fp32 -> bf16 chunked ----------------
__global__ __launch_bounds__(256) void cast_x_tiled_kernel(const float* __restrict__ in, u16* __restrict__ out) {
    int gi = (blockIdx.x * 256 + threadIdx.x) * 8;
    int row = gi >> 11, k = gi & 2047;
    const float4* p = reinterpret_cast<const float4*>(in + gi);
    float4 a = p[0], b = p[1];
    bf16x8 v;
    v[0] = (__bf16)a.x; v[1] = (__bf16)a.y; v[2] = (__bf16)a.z; v[3] = (__bf16)a.w;
    v[4] = (__bf16)b.x; v[5] = (__bf16)b.y; v[6] = (__bf16)b.z; v[7] = (__bf16)b.w;
    *reinterpret_cast<bf16x8*>(out + toff(row, k, DIMK)) = v;
}

// ---------------- single transpose: fp32 [KD][JD] -> bf16 chunked [JD][KD] ----------------
template <int KD, int JD>
__global__ __launch_bounds__(256) void trans_tiled_kernel(const float* __restrict__ in, u16* __restrict__ out) {
    __shared__ float tile[64 * 65];
    const int t = threadIdx.x;
    const float* ib = in + (size_t)blockIdx.z * KD * JD;
    u16* ob = out + (size_t)blockIdx.z * KD * JD;
    const int j0 = blockIdx.x * 64, k0 = blockIdx.y * 64;
    {
        const int c4 = (t & 15) * 4;
#pragma unroll
        for (int i = 0; i < 4; ++i) {
            const int r = (t >> 4) + i * 16;
            float4 v = *reinterpret_cast<const float4*>(&ib[(size_t)(k0 + r) * JD + j0 + c4]);
            tile[r * 65 + c4 + 0] = v.x;
            tile[r * 65 + c4 + 1] = v.y;
            tile[r * 65 + c4 + 2] = v.z;
            tile[r * 65 + c4 + 3] = v.w;
        }
    }
    __syncthreads();
    {
        const int jl = t >> 2, kh = (t & 3) * 16;
        const int n = j0 + jl;
        bf16x8 v0, v1;
#pragma unroll
        for (int j = 0; j < 8; ++j) v0[j] = (__bf16)tile[(kh + j) * 65 + jl];
#pragma unroll
        for (int j = 0; j < 8; ++j) v1[j] = (__bf16)tile[(kh + 8 + j) * 65 + jl];
        *reinterpret_cast<bf16x8*>(ob + toff(n, k0 + kh, KD)) = v0;
        *reinterpret_cast<bf16x8*>(ob + toff(n, k0 + kh + 8, KD)) = v1;
    }
}

// ---------------- cat transpose: wg,wu [KD][JD] -> Wcat chunked [2*JD][KD] ----------------
// Wcat row n <-> (s=(n>>4)&1, j=((n>>5)<<4)+(n&15)); 16-col interleave of gate/up.
template <int KD, int JD>
__global__ __launch_bounds__(256) void cat_trans_kernel(const float* __restrict__ g0, const float* __restrict__ u0,
                                                        u16* __restrict__ out) {
    __shared__ float tile[64 * 65];
    const int t = threadIdx.x;
    const size_t so = (size_t)blockIdx.z * KD * JD;
    u16* ob = out + (size_t)blockIdx.z * (2 * (size_t)KD * JD);
    const int j0 = blockIdx.x * 32, k0 = blockIdx.y * 64;
    const int kl = t >> 2, jf = (t & 3) * 4;
#pragma unroll
    for (int s = 0; s < 2; ++s) {
        const float* src = (s ? u0 : g0) + so;
#pragma unroll
        for (int rep = 0; rep < 2; ++rep) {
            int jb = jf + rep * 16;
            float4 v = *reinterpret_cast<const float4*>(&src[(size_t)(k0 + kl) * JD + j0 + jb]);
            int nl = ((jb >> 4) << 5) + s * 16 + (jb & 15);
            tile[kl * 65 + nl + 0] = v.x;
            tile[kl * 65 + nl + 1] = v.y;
            tile[kl * 65 + nl + 2] = v.z;
            tile[kl * 65 + nl + 3] = v.w;
        }
    }
    __syncthreads();
    {
        const int nl = t >> 2, kh = (t & 3) * 16;
        const int n = 2 * j0 + nl;
        bf16x8 v0, v1;
#pragma unroll
        for (int j = 0; j < 8; ++j) v0[j] = (__bf16)tile[(kh + j) * 65 + nl];
#pragma unroll
        for (int j = 0; j < 8; ++j) v1[j] = (__bf16)tile[(kh + 8 + j) * 65 + nl];
        *reinterpret_cast<bf16x8*>(ob + toff(n, k0 + kh, KD)) = v0;
        *reinterpret_cast<bf16x8*>(ob + toff(n, k0 + kh + 8, KD)) = v1;
    }
}

// ---------------- gate ----------------
__global__ __launch_bounds__(64) void gate_kernel(const float* __restrict__ x, const float* __restrict__ gw,
                                                  int* __restrict__ counts, int* __restrict__ ids,
                                                  float* __restrict__ wgts) {
    const int t = blockIdx.x;
    const int lane = threadIdx.x;
    __shared__ float logits[NEXP];
    const float4* xr = reinterpret_cast<const float4*>(x + (size_t)t * DIMK);
    for (int e = 0; e < NEXP; ++e) {
        const float4* gr = reinterpret_cast<const float4*>(gw + (size_t)e * DIMK);
        float acc = 0.f;
#pragma unroll
        for (int i = 0; i < DIMK / 4 / 64; ++i) {
            float4 xv = xr[lane + i * 64];
            float4 gv = gr[lane + i * 64];
            acc += xv.x * gv.x + xv.y * gv.y + xv.z * gv.z + xv.w * gv.w;
        }
#pragma unroll
        for (int s = 32; s; s >>= 1) acc += __shfl_xor(acc, s);
        if (lane == 0) logits[e] = acc;
    }
    if (lane != 0) return;
    float sc[NEXP];
#pragma unroll
    for (int e = 0; e < NEXP; ++e) sc[e] = logits[e];
    float mx = sc[0];
#pragma unroll
    for (int e = 1; e < NEXP; ++e) mx = fmaxf(mx, sc[e]);
    float ssum = 0.f;
#pragma unroll
    for (int e = 0; e < NEXP; ++e) { sc[e] = __expf(sc[e] - mx); ssum += sc[e]; }
    const float inv = 1.f / ssum;
    float gsc[NGRP];
#pragma unroll
    for (int g = 0; g < NGRP; ++g) {
        float m2 = sc[g * 4];
#pragma unroll
        for (int j = 1; j < 4; ++j) m2 = fmaxf(m2, sc[g * 4 + j]);
        gsc[g] = m2;
    }
    int gsel = 0;
    for (int r = 0; r < NTOPG; ++r) {
        float bv = -1.f; int bi = 0;
#pragma unroll
        for (int g = 0; g < NGRP; ++g) {
            bool c = (((gsel >> g) & 1) == 0) && (gsc[g] > bv);
            bv = c ? gsc[g] : bv; bi = c ? g : bi;
        }
        gsel |= (1 << bi);
    }
    float msk[NEXP];
#pragma unroll
    for (int e = 0; e < NEXP; ++e) msk[e] = ((gsel >> (e >> 2)) & 1) ? sc[e] : -1.f;
    for (int r = 0; r < NTOPK; ++r) {
        float bv = -3.f; int bi = 0;
#pragma unroll
        for (int e = 0; e < NEXP; ++e) {
            bool c = msk[e] > bv;
            bv = c ? msk[e] : bv; bi = c ? e : bi;
        }
#pragma unroll
        for (int e = 0; e < NEXP; ++e) if (e == bi) msk[e] = -2.f;
        float w = bv * inv;
        int slot = atomicAdd(&counts[bi], 1);
        ids[bi * T_TOK + slot] = t;
        wgts[bi * T_TOK + slot] = w;
    }
}

// ---------------- scan: 128-padded exclusive offsets ----------------
__global__ void scan_kernel(const int* __restrict__ counts, int* __restrict__ poff) {
    if (threadIdx.x == 0) {
        int o = 0;
        for (int e = 0; e < NEXP; ++e) { poff[e] = o; o += (counts[e] + 127) & ~127; }
    }
}

// ---------------- gather: x fp32 rows -> per-expert padded chunked bf16 A ----------------
__global__ __launch_bounds__(256) void gather_a_kernel(const float* __restrict__ x, const int* __restrict__ ids,
                                                       const int* __restrict__ counts, const int* __restrict__ poff,
                                                       u16* __restrict__ At) {
    const int e = blockIdx.y, bm = blockIdx.x;
    const int M = counts[e];
    if (bm * 128 >= M) return;
    const int t = threadIdx.x;
    const int r = t >> 1, h = t & 1;
    const int lr = bm * 128 + r;
    const int cr = lr < M ? lr : M - 1;
    const int tok = ids[e * T_TOK + cr];
    const float* src = x + (size_t)tok * DIMK;
    u16* dst = At + ((size_t)poff[e] + (size_t)bm * 128) * DIMK + r * 64;
    const int rx = r & 7;
#pragma unroll 2
    for (int kc = 0; kc < DIMK / 64; ++kc) {
#pragma unroll
        for (int gi = 0; gi < 4; ++gi) {
            int g = h * 4 + gi;
            const float* s = src + kc * 64 + g * 8;
            float4 f0 = *reinterpret_cast<const float4*>(s);
            float4 f1 = *reinterpret_cast<const float4*>(s + 4);
            bf16x8 v;
            v[0] = (__bf16)f0.x; v[1] = (__bf16)f0.y; v[2] = (__bf16)f0.z; v[3] = (__bf16)f0.w;
            v[4] = (__bf16)f1.x; v[5] = (__bf16)f1.y; v[6] = (__bf16)f1.z; v[7] = (__bf16)f1.w;
            *reinterpret_cast<bf16x8*>(dst + (size_t)kc * 8192 + ((g ^ rx) << 3)) = v;
        }
    }
}

// ================= 256x256 / BK=64 / 8-wave quadrant-phased GEMM =================
// GEMM1: H = silu(A*Wcat_g) * (A*Wcat_u), Wcat 16-col interleaved. NN = Wcat rows.
template <bool GATHER, int KK, int NN>
__global__ __launch_bounds__(512, 2) void gemm1_kernel(
    const u16* __restrict__ Abase, const u16* __restrict__ Bcat, u16* __restrict__ Hout,
    const int* __restrict__ counts, const int* __restrict__ poff, int Mshared) {
    __shared__ u16 Alds[4 * 8192];  // [buf][half][8192]
    __shared__ u16 Blds[4 * 8192];

    const int bm = blockIdx.x, bn = blockIdx.y, e = blockIdx.z;
    int M, Mpad, hbase;
    const u16 *a0, *b0;
    if (GATHER) {
        M = counts[e];
        if (bm * 256 >= M) return;
        Mpad = (M + 127) & ~127;
        hbase = poff[e];
        a0 = Abase + (size_t)poff[e] * KK;
        b0 = Bcat + (size_t)e * NN * KK;
    } else {
        M = Mshared; Mpad = Mshared; hbase = 0; a0 = Abase; b0 = Bcat;
        if (bm * 256 >= M) return;
    }
    const int tid = threadIdx.x, lane = tid & 63, wv = tid >> 6;
    const int wr = wv >> 2, wc = wv & 3;
    const int l15 = lane & 15, lk = lane >> 4;

    const u16* aCh[2] = { a0 + (size_t)(2 * bm + 0) * (128 * KK), a0 + (size_t)(2 * bm + 1) * (128 * KK) };
    const u16* bCh[2] = { b0 + (size_t)(2 * bn + 0) * (128 * KK), b0 + (size_t)(2 * bn + 1) * (128 * KK) };
    const int t8 = tid * 8;

    f32x4 acc[8][4];
#pragma unroll
    for (int m = 0; m < 8; ++m)
#pragma unroll
        for (int n = 0; n < 4; ++n) acc[m][n] = {0.f, 0.f, 0.f, 0.f};

    auto STG = [&](const u16* chBase, u16* lds, int kt, int buf, int half) {
        const u16* gs = chBase + (size_t)kt * 8192;
        u16* ld = lds + (buf * 2 + half) * 8192;
        glds16(gs + t8, ld + t8);
        glds16(gs + 4096 + t8, ld + 4096 + t8);
    };
    auto DSRA = [&](int buf, int mq, bf16x8 a[4][2]) {
#pragma unroll
        for (int mi = 0; mi < 4; ++mi)
#pragma unroll
            for (int ki = 0; ki < 2; ++ki) {
                int rl = mq * 64 + mi * 16 + l15;
                int g = ki * 4 + lk;
                a[mi][ki] = *reinterpret_cast<const bf16x8*>(&Alds[(buf * 2 + wr) * 8192 + rl * 64 + ((g ^ (rl & 7)) << 3)]);
            }
    };
    auto DSRB = [&](int buf, int nh, bf16x8 b[2][2]) {
#pragma unroll
        for (int ni = 0; ni < 2; ++ni)
#pragma unroll
            for (int ki = 0; ki < 2; ++ki) {
                int rc = (wc & 1) * 64 + nh * 32 + ni * 16 + l15;
                int g = ki * 4 + lk;
                b[ni][ki] = *reinterpret_cast<const bf16x8*>(&Blds[(buf * 2 + (wc >> 1)) * 8192 + rc * 64 + ((g ^ (rc & 7)) << 3)]);
            }
    };

    bf16x8 a[4][2], br0[2][2], br1[2][2];
    constexpr int NT = KK / 64;
    STG(aCh[0], Alds, 0, 0, 0);
    STG(aCh[1], Alds, 0, 0, 1);
    STG(bCh[0], Blds, 0, 0, 0);
    STG(bCh[1], Blds, 0, 0, 1);

#pragma unroll 1
    for (int t = 0; t < NT; ++t) {
        const int buf = t & 1, bufn = buf ^ 1;
        const bool pf = (t + 1) < NT;
        // ph1: quadrant (mq0, nh0)
        if (pf) {
            STG(aCh[0], Alds, t + 1, bufn, 0);
            asm volatile("s_waitcnt vmcnt(2)" ::: "memory");
        } else {
            asm volatile("s_waitcnt vmcnt(0)" ::: "memory");
        }
        __builtin_amdgcn_s_barrier();
        DSRA(buf, 0, a);
        DSRB(buf, 0, br0);
        __builtin_amdgcn_s_setprio(1);
#pragma unroll
        for (int ki = 0; ki < 2; ++ki)
#pragma unroll
            for (int mi = 0; mi < 4; ++mi)
#pragma unroll
                for (int ni = 0; ni < 2; ++ni)
                    acc[mi][ni] = __builtin_amdgcn_mfma_f32_16x16x32_bf16(a[mi][ki], br0[ni][ki], acc[mi][ni], 0, 0, 0);
        __builtin_amdgcn_s_setprio(0);
        // ph2: (mq0, nh1)
        DSRB(buf, 1, br1);
        if (pf) STG(aCh[1], Alds, t + 1, bufn, 1);
        __builtin_amdgcn_s_barrier();
        __builtin_amdgcn_s_setprio(1);
#pragma unroll
        for (int ki = 0; ki < 2; ++ki)
#pragma unroll
            for (int mi = 0; mi < 4; ++mi)
#pragma unroll
                for (int ni = 0; ni < 2; ++ni)
                    acc[mi][2 + ni] = __builtin_amdgcn_mfma_f32_16x16x32_bf16(a[mi][ki], br1[ni][ki], acc[mi][2 + ni], 0, 0, 0);
        __builtin_amdgcn_s_setprio(0);
        // ph3: (mq1, nh1)
        DSRA(buf, 1, a);
        if (pf) STG(bCh[0], Blds, t + 1, bufn, 0);
        __builtin_amdgcn_s_barrier();
        __builtin_amdgcn_s_setprio(1);
#pragma unroll
        for (int ki = 0; ki < 2; ++ki)
#pragma unroll
            for (int mi = 0; mi < 4; ++mi)
#pragma unroll
                for (int ni = 0; ni < 2; ++ni)
                    acc[4 + mi][2 + ni] = __builtin_amdgcn_mfma_f32_16x16x32_bf16(a[mi][ki], br1[ni][ki], acc[4 + mi][2 + ni], 0, 0, 0);
        __builtin_amdgcn_s_setprio(0);
        // ph4: (mq1, nh0)
        if (pf) STG(bCh[1], Blds, t + 1, bufn, 1);
        __builtin_amdgcn_s_barrier();
        __builtin_amdgcn_s_setprio(1);
#pragma unroll
        for (int ki = 0; ki < 2; ++ki)
#pragma unroll
            for (int mi = 0; mi < 4; ++mi)
#pragma unroll
                for (int ni = 0; ni < 2; ++ni)
                    acc[4 + mi][ni] = __builtin_amdgcn_mfma_f32_16x16x32_bf16(a[mi][ki], br0[ni][ki], acc[4 + mi][ni], 0, 0, 0);
        __builtin_amdgcn_s_setprio(0);
    }

    // epilogue: h = silu(g)*u -> H chunked (guard < Mpad; pad rows finite via clamped toks)
    constexpr int HK = NN / 2;
#pragma unroll
    for (int mI = 0; mI < 8; ++mI) {
#pragma unroll
        for (int r = 0; r < 4; ++r) {
            int rowt = wr * 128 + (mI >> 2) * 64 + (mI & 3) * 16 + lk * 4 + r;
            int grow = bm * 256 + rowt;
            if (grow < Mpad) {
#pragma unroll
                for (int nh = 0; nh < 2; ++nh) {
                    float gg = acc[mI][nh * 2 + 0][r];
                    float uu = acc[mI][nh * 2 + 1][r];
                    float h = gg / (1.f + __expf(-gg)) * uu;
                    int ic = bn * 128 + wc * 32 + nh * 16 + l15;
                    __bf16 hb = (__bf16)h;
                    Hout[toff(hbase + grow, ic, HK)] = __builtin_bit_cast(u16, hb);
                }
            }
        }
    }
}

// GEMM2: out[tok] += (H*Wd) * w ; SHARED: tok=row, w=1, 2-way K-split. NN=2048.
template <bool SHARED, int KK>
__global__ __launch_bounds__(512, 2) void gemm2_kernel(
    const u16* __restrict__ Hbase, const u16* __restrict__ Bd, float* __restrict__ out,
    const int* __restrict__ counts, const int* __restrict__ ids, const int* __restrict__ poff,
    const float* __restrict__ wgts, int Mshared) {
    __shared__ u16 Alds[4 * 8192];
    __shared__ u16 Blds[4 * 8192];

    const int bm = blockIdx.x, bn = blockIdx.y;
    constexpr int NT = SHARED ? (KK / 128) : (KK / 64);
    int M, e = 0, kt0 = 0;
    const u16 *a0, *b0;
    if (SHARED) {
        M = Mshared; a0 = Hbase; b0 = Bd;
        kt0 = blockIdx.z * NT;
    } else {
        e = blockIdx.z;
        M = counts[e];
        if (bm * 256 >= M) return;
        a0 = Hbase + (size_t)poff[e] * KK;
        b0 = Bd + (size_t)e * 2048 * KK;
    }
    const int tid = threadIdx.x, lane = tid & 63, wv = tid >> 6;
    const int wr = wv >> 2, wc = wv & 3;
    const int l15 = lane & 15, lk = lane >> 4;

    const u16* aCh[2] = { a0 + (size_t)(2 * bm + 0) * (128 * KK) + (size_t)kt0 * 8192,
                          a0 + (size_t)(2 * bm + 1) * (128 * KK) + (size_t)kt0 * 8192 };
    const u16* bCh[2] = { b0 + (size_t)(2 * bn + 0) * (128 * KK) + (size_t)kt0 * 8192,
                          b0 + (size_t)(2 * bn + 1) * (128 * KK) + (size_t)kt0 * 8192 };
    const int t8 = tid * 8;

    f32x4 acc[8][4];
#pragma unroll
    for (int m = 0; m < 8; ++m)
#pragma unroll
        for (int n = 0; n < 4; ++n) acc[m][n] = {0.f, 0.f, 0.f, 0.f};

    auto STG = [&](const u16* chBase, u16* lds, int kt, int buf, int half) {
        const u16* gs = chBase + (size_t)kt * 8192;
        u16* ld = lds + (buf * 2 + half) * 8192;
        glds16(gs + t8, ld + t8);
        glds16(gs + 4096 + t8, ld + 4096 + t8);
    };
    auto DSRA = [&](int buf, int mq, bf16x8 a[4][2]) {
#pragma unroll
        for (int mi = 0; mi < 4; ++mi)
#pragma unroll
            for (int ki = 0; ki < 2; ++ki) {
                int rl = mq * 64 + mi * 16 + l15;
                int g = ki * 4 + lk;
                a[mi][ki] = *reinterpret_cast<const bf16x8*>(&Alds[(buf * 2 + wr) * 8192 + rl * 64 + ((g ^ (rl & 7)) << 3)]);
            }
    };
    auto DSRB = [&](int buf, int nh, bf16x8 b[2][2]) {
#pragma unroll
        for (int ni = 0; ni < 2; ++ni)
#pragma unroll
            for (int ki = 0; ki < 2; ++ki) {
                int rc = (wc & 1) * 64 + nh * 32 + ni * 16 + l15;
                int g = ki * 4 + lk;
                b[ni][ki] = *reinterpret_cast<const bf16x8*>(&Blds[(buf * 2 + (wc >> 1)) * 8192 + rc * 64 + ((g ^ (rc & 7)) << 3)]);
            }
    };

    bf16x8 a[4][2], br0[2][2], br1[2][2];
    STG(aCh[0], Alds, 0, 0, 0);
    STG(aCh[1], Alds, 0, 0, 1);
    STG(bCh[0], Blds, 0, 0, 0);
    STG(bCh[1], Blds, 0, 0, 1);

#pragma unroll 1
    for (int t = 0; t < NT; ++t) {
        const int buf = t & 1, bufn = buf ^ 1;
        const bool pf = (t + 1) < NT;
        if (pf) {
            STG(aCh[0], Alds, t + 1, bufn, 0);
            asm volatile("s_waitcnt vmcnt(2)" ::: "memory");
        } else {
            asm volatile("s_waitcnt vmcnt(0)" ::: "memory");
        }
        __builtin_amdgcn_s_barrier();
        DSRA(buf, 0, a);
        DSRB(buf, 0, br0);
        __builtin_amdgcn_s_setprio(1);
#pragma unroll
        for (int ki = 0; ki < 2; ++ki)
#pragma unroll
            for (int mi = 0; mi < 4; ++mi)
#pragma unroll
                for (int ni = 0; ni < 2; ++ni)
                    acc[mi][ni] = __builtin_amdgcn_mfma_f32_16x16x32_bf16(a[mi][ki], br0[ni][ki], acc[mi][ni], 0, 0, 0);
        __builtin_amdgcn_s_setprio(0);
        DSRB(buf, 1, br1);
        if (pf) STG(aCh[1], Alds, t + 1, bufn, 1);
        __builtin_amdgcn_s_barrier();
        __builtin_amdgcn_s_setprio(1);
#pragma unroll
        for (int ki = 0; ki < 2; ++ki)
#pragma unroll
            for (int mi = 0; mi < 4; ++mi)
#pragma unroll
                for (int ni = 0; ni < 2; ++ni)
                    acc[mi][2 + ni] = __builtin_amdgcn_mfma_f32_16x16x32_bf16(a[mi][ki], br1[ni][ki], acc[mi][2 + ni], 0, 0, 0);
        __builtin_amdgcn_s_setprio(0);
        DSRA(buf, 1, a);
        if (pf) STG(bCh[0], Blds, t + 1, bufn, 0);
        __builtin_amdgcn_s_barrier();
        __builtin_amdgcn_s_setprio(1);
#pragma unroll
        for (int ki = 0; ki < 2; ++ki)
#pragma unroll
            for (int mi = 0; mi < 4; ++mi)
#pragma unroll
                for (int ni = 0; ni < 2; ++ni)
                    acc[4 + mi][2 + ni] = __builtin_amdgcn_mfma_f32_16x16x32_bf16(a[mi][ki], br1[ni][ki], acc[4 + mi][2 + ni], 0, 0, 0);
        __builtin_amdgcn_s_setprio(0);
        if (pf) STG(bCh[1], Blds, t + 1, bufn, 1);
        __builtin_amdgcn_s_barrier();
        __builtin_amdgcn_s_setprio(1);
#pragma unroll
        for (int ki = 0; ki < 2; ++ki)
#pragma unroll
            for (int mi = 0; mi < 4; ++mi)
#pragma unroll
                for (int ni = 0; ni < 2; ++ni)
                    acc[4 + mi][ni] = __builtin_amdgcn_mfma_f32_16x16x32_bf16(a[mi][ki], br0[ni][ki], acc[4 + mi][ni], 0, 0, 0);
        __builtin_amdgcn_s_setprio(0);
    }

#pragma unroll
    for (int mI = 0; mI < 8; ++mI) {
#pragma unroll
        for (int r = 0; r < 4; ++r) {
            int rowt = wr * 128 + (mI >> 2) * 64 + (mI & 3) * 16 + lk * 4 + r;
            int grow = bm * 256 + rowt;
            if (grow < M) {
                int tok; float w;
                if (SHARED) { tok = grow; w = 1.f; }
                else { tok = ids[e * T_TOK + grow]; w = wgts[e * T_TOK + grow]; }
#pragma unroll
                for (int nI = 0; nI < 4; ++nI) {
                    int col = bn * 256 + wc * 64 + (nI >> 1) * 32 + (nI & 1) * 16 + l15;
                    atomicAdd(&out[(size_t)tok * 2048 + col], acc[mI][nI][r] * w);
                }
            }
        }
    }
}

extern "C" void kernel_launch(void* const* d_in, const int* in_sizes, int n_in,
                              void* d_out, int out_size, void* d_ws, size_t ws_size,
                              hipStream_t stream) {
    const float* x = (const float*)d_in[0];
    const float* gate_w = (const float*)d_in[1];
    const float* wg = (const float*)d_in[2];
    const float* wu = (const float*)d_in[3];
    const float* wd = (const float*)d_in[4];
    const float* swg = (const float*)d_in[5];
    const float* swu = (const float*)d_in[6];
    const float* swd = (const float*)d_in[7];
    float* out = (float*)d_out;

    char* ws = (char*)d_ws;
    size_t off = 0;
    auto alloc = [&](size_t bytes) {
        void* p = ws + off;
        off = (off + bytes + 255) & ~(size_t)255;
        return p;
    };
    u16* xbT = (u16*)alloc((size_t)T_TOK * DIMK * 2);                  // 16.8 MB
    u16* At = (u16*)alloc((size_t)MAXPADROWS * DIMK * 2);              // 119.6 MB
    u16* H = (u16*)alloc((size_t)MAXPADROWS * INTERN * 2);             // 59.8 MB
    int* ids = (int*)alloc((size_t)NEXP * T_TOK * 4);
    float* wgts = (float*)alloc((size_t)NEXP * T_TOK * 4);
    int* counts = (int*)alloc(NEXP * 4);
    int* poff = (int*)alloc(NEXP * 4);
    u16* WcatS = (u16*)alloc((size_t)(2 * SINTER) * DIMK * 2);         // 16.8 MB
    u16* swdT = (u16*)alloc((size_t)DIMK * SINTER * 2);                // 8.4 MB
    u16* WcatE = (u16*)alloc((size_t)NEXP * (2 * INTERN) * DIMK * 2);  // 268.4 MB
    u16* wdT = WcatE;  // alias: wd transpose runs after GEMM1s consumed WcatE (stream-ordered)
    u16* Hs = At;      // alias: shared-H written after eGEMM1 consumed At (stream-ordered)

    hipMemsetAsync(counts, 0, NEXP * 4, stream);
    hipMemsetAsync(out, 0, (size_t)T_TOK * DIMK * 4, stream);
    cast_x_tiled_kernel<<<(T_TOK * DIMK) / (256 * 8), 256, 0, stream>>>(x, xbT);
    gate_kernel<<<T_TOK, 64, 0, stream>>>(x, gate_w, counts, ids, wgts);
    scan_kernel<<<1, 64, 0, stream>>>(counts, poff);
    gather_a_kernel<<<dim3(32, NEXP), 256, 0, stream>>>(x, ids, counts, poff, At);

    // weight reshapes: Wcat (gate/up 16-col interleaved, chunked+swz), swd transpose
    cat_trans_kernel<DIMK, SINTER><<<dim3(SINTER / 32, DIMK / 64, 1), 256, 0, stream>>>(swg, swu, WcatS);
    cat_trans_kernel<DIMK, INTERN><<<dim3(INTERN / 32, DIMK / 64, NEXP), 256, 0, stream>>>(wg, wu, WcatE);
    trans_tiled_kernel<SINTER, DIMK><<<dim3(DIMK / 64, SINTER / 64, 1), 256, 0, stream>>>(swd, swdT);

    // expert GEMM1: A=[Mpad][2048], Wcat=[2048][2048] per expert
    gemm1_kernel<true, DIMK, 2 * INTERN><<<dim3(16, (2 * INTERN) / 256, NEXP), 512, 0, stream>>>(
        At, WcatE, H, counts, poff, 0);
    // shared GEMM1: A=[4096][2048], Wcat=[4096][2048]
    gemm1_kernel<false, DIMK, 2 * SINTER><<<dim3(T_TOK / 256, (2 * SINTER) / 256, 1), 512, 0, stream>>>(
        xbT, WcatS, Hs, nullptr, nullptr, T_TOK);

    // wd transpose into aliased WcatE region (GEMM1s done by stream order)
    trans_tiled_kernel<INTERN, DIMK><<<dim3(DIMK / 64, INTERN / 64, NEXP), 256, 0, stream>>>(wd, wdT);

    // shared GEMM2: K=2048, 2-way K-split, atomic into zeroed out
    gemm2_kernel<true, SINTER><<<dim3(T_TOK / 256, DIMK / 256, 2), 512, 0, stream>>>(
        Hs, swdT, out, nullptr, nullptr, nullptr, nullptr, T_TOK);
    // expert GEMM2: K=1024, atomic with routing weights
    gemm2_kernel<false, INTERN><<<dim3(16, DIMK / 256, NEXP), 512, 0, stream>>>(
        H, wdT, out, counts, ids, poff, wgts, 0);
}

// Round 7
// 1429.322 us; speedup vs baseline: 1.9091x; 1.9091x over previous
//
#include <hip/hip_runtime.h>
#include <hip/hip_bf16.h>

typedef float f32x4 __attribute__((ext_vector_type(4)));
typedef __bf16 bf16x8 __attribute__((ext_vector_type(8)));
typedef unsigned short u16;

#define T_TOK 4096
#define DIMK 2048
#define INTERN 1024
#define NEXP 32
#define NTOPK 6
#define NGRP 8
#define NTOPG 4
#define SINTER 2048
#define MAXPADROWS 29184

// async global->LDS 16B
__device__ __forceinline__ void glds16(const void* g, void* l) {
    auto* gp = (const __attribute__((address_space(1))) int*)(g);
    auto* lp = (__attribute__((address_space(3))) int*)(l);
    __builtin_amdgcn_global_load_lds(gp, lp, 16, 0, 0);
}

// Chunked+swizzled layout for [Rows][K] bf16: row-chunks of 128, k-chunks of 64.
// chunk order: [rowchunk][kchunk] (kchunk fastest). In-chunk (16KB):
//   off = row*64 + ((g ^ (row&7))<<3) + (k&7),  g = (k>>3)&7.
__device__ __forceinline__ size_t toff(int row, int k, int K) {
    int g = (k >> 3) & 7;
    return (size_t)(row >> 7) * (size_t)(128 * K) + (size_t)(k >> 6) * 8192 +
           (size_t)((row & 127) * 64 + ((g ^ (row & 7)) << 3) + (k & 7));
}

// ---------------- cast x fp32 -> bf16 chunked ----------------
__global__ __launch_bounds__(256) void cast_x_tiled_kernel(const float* __restrict__ in, u16* __restrict__ out) {
    int gi = (blockIdx.x * 256 + threadIdx.x) * 8;
    int row = gi >> 11, k = gi & 2047;
    const float4* p = reinterpret_cast<const float4*>(in + gi);
    float4 a = p[0], b = p[1];
    bf16x8 v;
    v[0] = (__bf16)a.x; v[1] = (__bf16)a.y; v[2] = (__bf16)a.z; v[3] = (__bf16)a.w;
    v[4] = (__bf16)b.x; v[5] = (__bf16)b.y; v[6] = (__bf16)b.z; v[7] = (__bf16)b.w;
    *reinterpret_cast<bf16x8*>(out + toff(row, k, DIMK)) = v;
}

// ---------------- single transpose: fp32 [KD][JD] -> bf16 chunked [JD][KD] ----------------
template <int KD, int JD>
__global__ __launch_bounds__(256) void trans_tiled_kernel(const float* __restrict__ in, u16* __restrict__ out) {
    __shared__ float tile[64 * 65];
    const int t = threadIdx.x;
    const float* ib = in + (size_t)blockIdx.z * KD * JD;
    u16* ob = out + (size_t)blockIdx.z * KD * JD;
    const int j0 = blockIdx.x * 64, k0 = blockIdx.y * 64;
    {
        const int c4 = (t & 15) * 4;
#pragma unroll
        for (int i = 0; i < 4; ++i) {
            const int r = (t >> 4) + i * 16;
            float4 v = *reinterpret_cast<const float4*>(&ib[(size_t)(k0 + r) * JD + j0 + c4]);
            tile[r * 65 + c4 + 0] = v.x;
            tile[r * 65 + c4 + 1] = v.y;
            tile[r * 65 + c4 + 2] = v.z;
            tile[r * 65 + c4 + 3] = v.w;
        }
    }
    __syncthreads();
    {
        const int jl = t >> 2, kh = (t & 3) * 16;
        const int n = j0 + jl;
        bf16x8 v0, v1;
#pragma unroll
        for (int j = 0; j < 8; ++j) v0[j] = (__bf16)tile[(kh + j) * 65 + jl];
#pragma unroll
        for (int j = 0; j < 8; ++j) v1[j] = (__bf16)tile[(kh + 8 + j) * 65 + jl];
        *reinterpret_cast<bf16x8*>(ob + toff(n, k0 + kh, KD)) = v0;
        *reinterpret_cast<bf16x8*>(ob + toff(n, k0 + kh + 8, KD)) = v1;
    }
}

// ---------------- cat transpose: wg,wu [KD][JD] -> Wcat chunked [2*JD][KD] ----------------
// Wcat row n <-> (s=(n>>4)&1, j=((n>>5)<<4)+(n&15)); 16-col interleave of gate/up.
template <int KD, int JD>
__global__ __launch_bounds__(256) void cat_trans_kernel(const float* __restrict__ g0, const float* __restrict__ u0,
                                                        u16* __restrict__ out) {
    __shared__ float tile[64 * 65];
    const int t = threadIdx.x;
    const size_t so = (size_t)blockIdx.z * KD * JD;
    u16* ob = out + (size_t)blockIdx.z * (2 * (size_t)KD * JD);
    const int j0 = blockIdx.x * 32, k0 = blockIdx.y * 64;
    const int kl = t >> 2, jf = (t & 3) * 4;
#pragma unroll
    for (int s = 0; s < 2; ++s) {
        const float* src = (s ? u0 : g0) + so;
#pragma unroll
        for (int rep = 0; rep < 2; ++rep) {
            int jb = jf + rep * 16;
            float4 v = *reinterpret_cast<const float4*>(&src[(size_t)(k0 + kl) * JD + j0 + jb]);
            int nl = ((jb >> 4) << 5) + s * 16 + (jb & 15);
            tile[kl * 65 + nl + 0] = v.x;
            tile[kl * 65 + nl + 1] = v.y;
            tile[kl * 65 + nl + 2] = v.z;
            tile[kl * 65 + nl + 3] = v.w;
        }
    }
    __syncthreads();
    {
        const int nl = t >> 2, kh = (t & 3) * 16;
        const int n = 2 * j0 + nl;
        bf16x8 v0, v1;
#pragma unroll
        for (int j = 0; j < 8; ++j) v0[j] = (__bf16)tile[(kh + j) * 65 + nl];
#pragma unroll
        for (int j = 0; j < 8; ++j) v1[j] = (__bf16)tile[(kh + 8 + j) * 65 + nl];
        *reinterpret_cast<bf16x8*>(ob + toff(n, k0 + kh, KD)) = v0;
        *reinterpret_cast<bf16x8*>(ob + toff(n, k0 + kh + 8, KD)) = v1;
    }
}

// ---------------- gate ----------------
__global__ __launch_bounds__(64) void gate_kernel(const float* __restrict__ x, const float* __restrict__ gw,
                                                  int* __restrict__ counts, int* __restrict__ ids,
                                                  float* __restrict__ wgts) {
    const int t = blockIdx.x;
    const int lane = threadIdx.x;
    __shared__ float logits[NEXP];
    const float4* xr = reinterpret_cast<const float4*>(x + (size_t)t * DIMK);
    for (int e = 0; e < NEXP; ++e) {
        const float4* gr = reinterpret_cast<const float4*>(gw + (size_t)e * DIMK);
        float acc = 0.f;
#pragma unroll
        for (int i = 0; i < DIMK / 4 / 64; ++i) {
            float4 xv = xr[lane + i * 64];
            float4 gv = gr[lane + i * 64];
            acc += xv.x * gv.x + xv.y * gv.y + xv.z * gv.z + xv.w * gv.w;
        }
#pragma unroll
        for (int s = 32; s; s >>= 1) acc += __shfl_xor(acc, s);
        if (lane == 0) logits[e] = acc;
    }
    if (lane != 0) return;
    float sc[NEXP];
#pragma unroll
    for (int e = 0; e < NEXP; ++e) sc[e] = logits[e];
    float mx = sc[0];
#pragma unroll
    for (int e = 1; e < NEXP; ++e) mx = fmaxf(mx, sc[e]);
    float ssum = 0.f;
#pragma unroll
    for (int e = 0; e < NEXP; ++e) { sc[e] = __expf(sc[e] - mx); ssum += sc[e]; }
    const float inv = 1.f / ssum;
    float gsc[NGRP];
#pragma unroll
    for (int g = 0; g < NGRP; ++g) {
        float m2 = sc[g * 4];
#pragma unroll
        for (int j = 1; j < 4; ++j) m2 = fmaxf(m2, sc[g * 4 + j]);
        gsc[g] = m2;
    }
    int gsel = 0;
    for (int r = 0; r < NTOPG; ++r) {
        float bv = -1.f; int bi = 0;
#pragma unroll
        for (int g = 0; g < NGRP; ++g) {
            bool c = (((gsel >> g) & 1) == 0) && (gsc[g] > bv);
            bv = c ? gsc[g] : bv; bi = c ? g : bi;
        }
        gsel |= (1 << bi);
    }
    float msk[NEXP];
#pragma unroll
    for (int e = 0; e < NEXP; ++e) msk[e] = ((gsel >> (e >> 2)) & 1) ? sc[e] : -1.f;
    for (int r = 0; r < NTOPK; ++r) {
        float bv = -3.f; int bi = 0;
#pragma unroll
        for (int e = 0; e < NEXP; ++e) {
            bool c = msk[e] > bv;
            bv = c ? msk[e] : bv; bi = c ? e : bi;
        }
#pragma unroll
        for (int e = 0; e < NEXP; ++e) if (e == bi) msk[e] = -2.f;
        float w = bv * inv;
        int slot = atomicAdd(&counts[bi], 1);
        ids[bi * T_TOK + slot] = t;
        wgts[bi * T_TOK + slot] = w;
    }
}

// ---------------- scan: 128-padded exclusive offsets ----------------
__global__ void scan_kernel(const int* __restrict__ counts, int* __restrict__ poff) {
    if (threadIdx.x == 0) {
        int o = 0;
        for (int e = 0; e < NEXP; ++e) { poff[e] = o; o += (counts[e] + 127) & ~127; }
    }
}

// ---------------- gather: x fp32 rows -> per-expert padded chunked bf16 A ----------------
__global__ __launch_bounds__(256) void gather_a_kernel(const float* __restrict__ x, const int* __restrict__ ids,
                                                       const int* __restrict__ counts, const int* __restrict__ poff,
                                                       u16* __restrict__ At) {
    const int e = blockIdx.y, bm = blockIdx.x;
    const int M = counts[e];
    if (bm * 128 >= M) return;
    const int t = threadIdx.x;
    const int r = t >> 1, h = t & 1;
    const int lr = bm * 128 + r;
    const int cr = lr < M ? lr : M - 1;
    const int tok = ids[e * T_TOK + cr];
    const float* src = x + (size_t)tok * DIMK;
    u16* dst = At + ((size_t)poff[e] + (size_t)bm * 128) * DIMK + r * 64;
    const int rx = r & 7;
#pragma unroll 2
    for (int kc = 0; kc < DIMK / 64; ++kc) {
#pragma unroll
        for (int gi = 0; gi < 4; ++gi) {
            int g = h * 4 + gi;
            const float* s = src + kc * 64 + g * 8;
            float4 f0 = *reinterpret_cast<const float4*>(s);
            float4 f1 = *reinterpret_cast<const float4*>(s + 4);
            bf16x8 v;
            v[0] = (__bf16)f0.x; v[1] = (__bf16)f0.y; v[2] = (__bf16)f0.z; v[3] = (__bf16)f0.w;
            v[4] = (__bf16)f1.x; v[5] = (__bf16)f1.y; v[6] = (__bf16)f1.z; v[7] = (__bf16)f1.w;
            *reinterpret_cast<bf16x8*>(dst + (size_t)kc * 8192 + ((g ^ rx) << 3)) = v;
        }
    }
}

// ================= 256x256 / BK=64 / 8-wave quadrant-phased GEMM =================
// GEMM1: H = silu(A*Wcat_g) * (A*Wcat_u), Wcat 16-col interleaved. NN = Wcat rows.
template <bool GATHER, int KK, int NN>
__global__ __launch_bounds__(512, 2) void gemm1_kernel(
    const u16* __restrict__ Abase, const u16* __restrict__ Bcat, u16* __restrict__ Hout,
    const int* __restrict__ counts, const int* __restrict__ poff, int Mshared) {
    __shared__ u16 Alds[4 * 8192];  // [buf][half][8192]
    __shared__ u16 Blds[4 * 8192];

    int bm, bn, e;
    if (GATHER) {
        // XCD-pinned (e & 7 == dispatch lin & 7), bm-inner; reversed expert order for L3 warmth
        int lin = blockIdx.x + 16 * (blockIdx.y + 8 * blockIdx.z);   // grid (16,8,32)
        e = (NEXP - 1) - (((lin >> 10) << 3) | (lin & 7));
        int j = (lin >> 3) & 127;
        bn = j >> 4; bm = j & 15;
    } else {
        // bijective XCD swizzle for 256-block grid (16,16)
        int lin = blockIdx.x + 16 * blockIdx.y;
        int swz = (lin & 7) * 32 + (lin >> 3);
        bm = swz & 15; bn = swz >> 4; e = 0;
    }

    int M, Mpad, hbase;
    const u16 *a0, *b0;
    if (GATHER) {
        M = counts[e];
        if (bm * 256 >= M) return;
        Mpad = (M + 127) & ~127;
        hbase = poff[e];
        a0 = Abase + (size_t)poff[e] * KK;
        b0 = Bcat + (size_t)e * NN * KK;
    } else {
        M = Mshared; Mpad = Mshared; hbase = 0; a0 = Abase; b0 = Bcat;
        if (bm * 256 >= M) return;
    }
    const int tid = threadIdx.x, lane = tid & 63, wv = tid >> 6;
    const int wr = wv >> 2, wc = wv & 3;
    const int l15 = lane & 15, lk = lane >> 4;

    const u16* aCh[2] = { a0 + (size_t)(2 * bm + 0) * (128 * KK), a0 + (size_t)(2 * bm + 1) * (128 * KK) };
    const u16* bCh[2] = { b0 + (size_t)(2 * bn + 0) * (128 * KK), b0 + (size_t)(2 * bn + 1) * (128 * KK) };
    const int t8 = tid * 8;

    f32x4 acc[8][4];
#pragma unroll
    for (int m = 0; m < 8; ++m)
#pragma unroll
        for (int n = 0; n < 4; ++n) acc[m][n] = {0.f, 0.f, 0.f, 0.f};

    auto STG = [&](const u16* chBase, u16* lds, int kt, int buf, int half) {
        const u16* gs = chBase + (size_t)kt * 8192;
        u16* ld = lds + (buf * 2 + half) * 8192;
        glds16(gs + t8, ld + t8);
        glds16(gs + 4096 + t8, ld + 4096 + t8);
    };
    auto DSRA = [&](int buf, int mq, bf16x8 a[4][2]) {
#pragma unroll
        for (int mi = 0; mi < 4; ++mi)
#pragma unroll
            for (int ki = 0; ki < 2; ++ki) {
                int rl = mq * 64 + mi * 16 + l15;
                int g = ki * 4 + lk;
                a[mi][ki] = *reinterpret_cast<const bf16x8*>(&Alds[(buf * 2 + wr) * 8192 + rl * 64 + ((g ^ (rl & 7)) << 3)]);
            }
    };
    auto DSRB = [&](int buf, int nh, bf16x8 b[2][2]) {
#pragma unroll
        for (int ni = 0; ni < 2; ++ni)
#pragma unroll
            for (int ki = 0; ki < 2; ++ki) {
                int rc = (wc & 1) * 64 + nh * 32 + ni * 16 + l15;
                int g = ki * 4 + lk;
                b[ni][ki] = *reinterpret_cast<const bf16x8*>(&Blds[(buf * 2 + (wc >> 1)) * 8192 + rc * 64 + ((g ^ (rc & 7)) << 3)]);
            }
    };

    bf16x8 a[4][2], br0[2][2], br1[2][2];
    constexpr int NT = KK / 64;
    STG(aCh[0], Alds, 0, 0, 0);
    STG(aCh[1], Alds, 0, 0, 1);
    STG(bCh[0], Blds, 0, 0, 0);
    STG(bCh[1], Blds, 0, 0, 1);

#pragma unroll 1
    for (int t = 0; t < NT; ++t) {
        const int buf = t & 1, bufn = buf ^ 1;
        const bool pf = (t + 1) < NT;
        // ph1: quadrant (mq0, nh0)
        if (pf) {
            STG(aCh[0], Alds, t + 1, bufn, 0);
            asm volatile("s_waitcnt vmcnt(2)" ::: "memory");
        } else {
            asm volatile("s_waitcnt vmcnt(0)" ::: "memory");
        }
        __builtin_amdgcn_s_barrier();
        DSRA(buf, 0, a);
        DSRB(buf, 0, br0);
        __builtin_amdgcn_s_setprio(1);
#pragma unroll
        for (int ki = 0; ki < 2; ++ki)
#pragma unroll
            for (int mi = 0; mi < 4; ++mi)
#pragma unroll
                for (int ni = 0; ni < 2; ++ni)
                    acc[mi][ni] = __builtin_amdgcn_mfma_f32_16x16x32_bf16(a[mi][ki], br0[ni][ki], acc[mi][ni], 0, 0, 0);
        __builtin_amdgcn_s_setprio(0);
        // ph2: (mq0, nh1)
        DSRB(buf, 1, br1);
        if (pf) STG(aCh[1], Alds, t + 1, bufn, 1);
        __builtin_amdgcn_s_barrier();
        __builtin_amdgcn_s_setprio(1);
#pragma unroll
        for (int ki = 0; ki < 2; ++ki)
#pragma unroll
            for (int mi = 0; mi < 4; ++mi)
#pragma unroll
                for (int ni = 0; ni < 2; ++ni)
                    acc[mi][2 + ni] = __builtin_amdgcn_mfma_f32_16x16x32_bf16(a[mi][ki], br1[ni][ki], acc[mi][2 + ni], 0, 0, 0);
        __builtin_amdgcn_s_setprio(0);
        // ph3: (mq1, nh1)
        DSRA(buf, 1, a);
        if (pf) STG(bCh[0], Blds, t + 1, bufn, 0);
        __builtin_amdgcn_s_barrier();
        __builtin_amdgcn_s_setprio(1);
#pragma unroll
        for (int ki = 0; ki < 2; ++ki)
#pragma unroll
            for (int mi = 0; mi < 4; ++mi)
#pragma unroll
                for (int ni = 0; ni < 2; ++ni)
                    acc[4 + mi][2 + ni] = __builtin_amdgcn_mfma_f32_16x16x32_bf16(a[mi][ki], br1[ni][ki], acc[4 + mi][2 + ni], 0, 0, 0);
        __builtin_amdgcn_s_setprio(0);
        // ph4: (mq1, nh0)
        if (pf) STG(bCh[1], Blds, t + 1, bufn, 1);
        __builtin_amdgcn_s_barrier();
        __builtin_amdgcn_s_setprio(1);
#pragma unroll
        for (int ki = 0; ki < 2; ++ki)
#pragma unroll
            for (int mi = 0; mi < 4; ++mi)
#pragma unroll
                for (int ni = 0; ni < 2; ++ni)
                    acc[4 + mi][ni] = __builtin_amdgcn_mfma_f32_16x16x32_bf16(a[mi][ki], br0[ni][ki], acc[4 + mi][ni], 0, 0, 0);
        __builtin_amdgcn_s_setprio(0);
    }

    // epilogue: h = silu(g)*u -> H chunked (guard < Mpad; pad rows finite via clamped toks)
    constexpr int HK = NN / 2;
#pragma unroll
    for (int mI = 0; mI < 8; ++mI) {
#pragma unroll
        for (int r = 0; r < 4; ++r) {
            int rowt = wr * 128 + (mI >> 2) * 64 + (mI & 3) * 16 + lk * 4 + r;
            int grow = bm * 256 + rowt;
            if (grow < Mpad) {
#pragma unroll
                for (int nh = 0; nh < 2; ++nh) {
                    float gg = acc[mI][nh * 2 + 0][r];
                    float uu = acc[mI][nh * 2 + 1][r];
                    float h = gg / (1.f + __expf(-gg)) * uu;
                    int ic = bn * 128 + wc * 32 + nh * 16 + l15;
                    __bf16 hb = (__bf16)h;
                    Hout[toff(hbase + grow, ic, HK)] = __builtin_bit_cast(u16, hb);
                }
            }
        }
    }
}

// GEMM2: out[tok] += (H*Wd) * w ; SHARED: tok=row, w=1, 2-way K-split. NN=2048.
template <bool SHARED, int KK>
__global__ __launch_bounds__(512, 2) void gemm2_kernel(
    const u16* __restrict__ Hbase, const u16* __restrict__ Bd, float* __restrict__ out,
    const int* __restrict__ counts, const int* __restrict__ ids, const int* __restrict__ poff,
    const float* __restrict__ wgts, int Mshared) {
    __shared__ u16 Alds[4 * 8192];
    __shared__ u16 Blds[4 * 8192];

    constexpr int NT = SHARED ? (KK / 128) : (KK / 64);
    int bm, bn, e = 0, kt0 = 0;
    if (SHARED) {
        // bijective XCD swizzle for 256-block grid (16,8,2)
        int lin = blockIdx.x + 16 * (blockIdx.y + 8 * blockIdx.z);
        int swz = (lin & 7) * 32 + (lin >> 3);
        bm = swz & 15; bn = (swz >> 4) & 7; kt0 = (swz >> 7) * NT;
    } else {
        int lin = blockIdx.x + 16 * (blockIdx.y + 8 * blockIdx.z);   // grid (16,8,32)
        e = (NEXP - 1) - (((lin >> 10) << 3) | (lin & 7));
        int j = (lin >> 3) & 127;
        bn = j >> 4; bm = j & 15;
    }

    int M;
    const u16 *a0, *b0;
    if (SHARED) {
        M = Mshared; a0 = Hbase; b0 = Bd;
    } else {
        M = counts[e];
        if (bm * 256 >= M) return;
        a0 = Hbase + (size_t)poff[e] * KK;
        b0 = Bd + (size_t)e * 2048 * KK;
    }
    const int tid = threadIdx.x, lane = tid & 63, wv = tid >> 6;
    const int wr = wv >> 2, wc = wv & 3;
    const int l15 = lane & 15, lk = lane >> 4;

    const u16* aCh[2] = { a0 + (size_t)(2 * bm + 0) * (128 * KK) + (size_t)kt0 * 8192,
                          a0 + (size_t)(2 * bm + 1) * (128 * KK) + (size_t)kt0 * 8192 };
    const u16* bCh[2] = { b0 + (size_t)(2 * bn + 0) * (128 * KK) + (size_t)kt0 * 8192,
                          b0 + (size_t)(2 * bn + 1) * (128 * KK) + (size_t)kt0 * 8192 };
    const int t8 = tid * 8;

    f32x4 acc[8][4];
#pragma unroll
    for (int m = 0; m < 8; ++m)
#pragma unroll
        for (int n = 0; n < 4; ++n) acc[m][n] = {0.f, 0.f, 0.f, 0.f};

    auto STG = [&](const u16* chBase, u16* lds, int kt, int buf, int half) {
        const u16* gs = chBase + (size_t)kt * 8192;
        u16* ld = lds + (buf * 2 + half) * 8192;
        glds16(gs + t8, ld + t8);
        glds16(gs + 4096 + t8, ld + 4096 + t8);
    };
    auto DSRA = [&](int buf, int mq, bf16x8 a[4][2]) {
#pragma unroll
        for (int mi = 0; mi < 4; ++mi)
#pragma unroll
            for (int ki = 0; ki < 2; ++ki) {
                int rl = mq * 64 + mi * 16 + l15;
                int g = ki * 4 + lk;
                a[mi][ki] = *reinterpret_cast<const bf16x8*>(&Alds[(buf * 2 + wr) * 8192 + rl * 64 + ((g ^ (rl & 7)) << 3)]);
            }
    };
    auto DSRB = [&](int buf, int nh, bf16x8 b[2][2]) {
#pragma unroll
        for (int ni = 0; ni < 2; ++ni)
#pragma unroll
            for (int ki = 0; ki < 2; ++ki) {
                int rc = (wc & 1) * 64 + nh * 32 + ni * 16 + l15;
                int g = ki * 4 + lk;
                b[ni][ki] = *reinterpret_cast<const bf16x8*>(&Blds[(buf * 2 + (wc >> 1)) * 8192 + rc * 64 + ((g ^ (rc & 7)) << 3)]);
            }
    };

    bf16x8 a[4][2], br0[2][2], br1[2][2];
    STG(aCh[0], Alds, 0, 0, 0);
    STG(aCh[1], Alds, 0, 0, 1);
    STG(bCh[0], Blds, 0, 0, 0);
    STG(bCh[1], Blds, 0, 0, 1);

#pragma unroll 1
    for (int t = 0; t < NT; ++t) {
        const int buf = t & 1, bufn = buf ^ 1;
        const bool pf = (t + 1) < NT;
        if (pf) {
            STG(aCh[0], Alds, t + 1, bufn, 0);
            asm volatile("s_waitcnt vmcnt(2)" ::: "memory");
        } else {
            asm volatile("s_waitcnt vmcnt(0)" ::: "memory");
        }
        __builtin_amdgcn_s_barrier();
        DSRA(buf, 0, a);
        DSRB(buf, 0, br0);
        __builtin_amdgcn_s_setprio(1);
#pragma unroll
        for (int ki = 0; ki < 2; ++ki)
#pragma unroll
            for (int mi = 0; mi < 4; ++mi)
#pragma unroll
                for (int ni = 0; ni < 2; ++ni)
                    acc[mi][ni] = __builtin_amdgcn_mfma_f32_16x16x32_bf16(a[mi][ki], br0[ni][ki], acc[mi][ni], 0, 0, 0);
        __builtin_amdgcn_s_setprio(0);
        DSRB(buf, 1, br1);
        if (pf) STG(aCh[1], Alds, t + 1, bufn, 1);
        __builtin_amdgcn_s_barrier();
        __builtin_amdgcn_s_setprio(1);
#pragma unroll
        for (int ki = 0; ki < 2; ++ki)
#pragma unroll
            for (int mi = 0; mi < 4; ++mi)
#pragma unroll
                for (int ni = 0; ni < 2; ++ni)
                    acc[mi][2 + ni] = __builtin_amdgcn_mfma_f32_16x16x32_bf16(a[mi][ki], br1[ni][ki], acc[mi][2 + ni], 0, 0, 0);
        __builtin_amdgcn_s_setprio(0);
        DSRA(buf, 1, a);
        if (pf) STG(bCh[0], Blds, t + 1, bufn, 0);
        __builtin_amdgcn_s_barrier();
        __builtin_amdgcn_s_setprio(1);
#pragma unroll
        for (int ki = 0; ki < 2; ++ki)
#pragma unroll
            for (int mi = 0; mi < 4; ++mi)
#pragma unroll
                for (int ni = 0; ni < 2; ++ni)
                    acc[4 + mi][2 + ni] = __builtin_amdgcn_mfma_f32_16x16x32_bf16(a[mi][ki], br1[ni][ki], acc[4 + mi][2 + ni], 0, 0, 0);
        __builtin_amdgcn_s_setprio(0);
        if (pf) STG(bCh[1], Blds, t + 1, bufn, 1);
        __builtin_amdgcn_s_barrier();
        __builtin_amdgcn_s_setprio(1);
#pragma unroll
        for (int ki = 0; ki < 2; ++ki)
#pragma unroll
            for (int mi = 0; mi < 4; ++mi)
#pragma unroll
                for (int ni = 0; ni < 2; ++ni)
                    acc[4 + mi][ni] = __builtin_amdgcn_mfma_f32_16x16x32_bf16(a[mi][ki], br0[ni][ki], acc[4 + mi][ni], 0, 0, 0);
        __builtin_amdgcn_s_setprio(0);
    }

#pragma unroll
    for (int mI = 0; mI < 8; ++mI) {
#pragma unroll
        for (int r = 0; r < 4; ++r) {
            int rowt = wr * 128 + (mI >> 2) * 64 + (mI & 3) * 16 + lk * 4 + r;
            int grow = bm * 256 + rowt;
            if (grow < M) {
                int tok; float w;
                if (SHARED) { tok = grow; w = 1.f; }
                else { tok = ids[e * T_TOK + grow]; w = wgts[e * T_TOK + grow]; }
#pragma unroll
                for (int nI = 0; nI < 4; ++nI) {
                    int col = bn * 256 + wc * 64 + (nI >> 1) * 32 + (nI & 1) * 16 + l15;
                    atomicAdd(&out[(size_t)tok * 2048 + col], acc[mI][nI][r] * w);
                }
            }
        }
    }
}

extern "C" void kernel_launch(void* const* d_in, const int* in_sizes, int n_in,
                              void* d_out, int out_size, void* d_ws, size_t ws_size,
                              hipStream_t stream) {
    const float* x = (const float*)d_in[0];
    const float* gate_w = (const float*)d_in[1];
    const float* wg = (const float*)d_in[2];
    const float* wu = (const float*)d_in[3];
    const float* wd = (const float*)d_in[4];
    const float* swg = (const float*)d_in[5];
    const float* swu = (const float*)d_in[6];
    const float* swd = (const float*)d_in[7];
    float* out = (float*)d_out;

    char* ws = (char*)d_ws;
    size_t off = 0;
    auto alloc = [&](size_t bytes) {
        void* p = ws + off;
        off = (off + bytes + 255) & ~(size_t)255;
        return p;
    };
    u16* xbT = (u16*)alloc((size_t)T_TOK * DIMK * 2);                  // 16.8 MB
    u16* At = (u16*)alloc((size_t)MAXPADROWS * DIMK * 2);              // 119.6 MB
    u16* H = (u16*)alloc((size_t)MAXPADROWS * INTERN * 2);             // 59.8 MB
    int* ids = (int*)alloc((size_t)NEXP * T_TOK * 4);
    float* wgts = (float*)alloc((size_t)NEXP * T_TOK * 4);
    int* counts = (int*)alloc(NEXP * 4);
    int* poff = (int*)alloc(NEXP * 4);
    u16* WcatS = (u16*)alloc((size_t)(2 * SINTER) * DIMK * 2);         // 16.8 MB
    u16* swdT = (u16*)alloc((size_t)DIMK * SINTER * 2);                // 8.4 MB
    u16* WcatE = (u16*)alloc((size_t)NEXP * (2 * INTERN) * DIMK * 2);  // 268.4 MB
    u16* wdT = WcatE;  // alias: wd transpose runs after eGEMM1 consumed WcatE (stream-ordered)
    u16* Hs = At;      // alias: shared-H written after eGEMM1 consumed At (stream-ordered)

    hipMemsetAsync(counts, 0, NEXP * 4, stream);
    hipMemsetAsync(out, 0, (size_t)T_TOK * DIMK * 4, stream);
    cast_x_tiled_kernel<<<(T_TOK * DIMK) / (256 * 8), 256, 0, stream>>>(x, xbT);
    gate_kernel<<<T_TOK, 64, 0, stream>>>(x, gate_w, counts, ids, wgts);
    scan_kernel<<<1, 64, 0, stream>>>(counts, poff);
    gather_a_kernel<<<dim3(32, NEXP), 256, 0, stream>>>(x, ids, counts, poff, At);

    // weight reshapes: Wcat (gate/up 16-col interleaved, chunked+swz), swd transpose
    cat_trans_kernel<DIMK, SINTER><<<dim3(SINTER / 32, DIMK / 64, 1), 256, 0, stream>>>(swg, swu, WcatS);
    cat_trans_kernel<DIMK, INTERN><<<dim3(INTERN / 32, DIMK / 64, NEXP), 256, 0, stream>>>(wg, wu, WcatE);
    trans_tiled_kernel<SINTER, DIMK><<<dim3(DIMK / 64, SINTER / 64, 1), 256, 0, stream>>>(swd, swdT);

    // expert GEMM1 (L3-warm experts first via reversed order): A=[Mpad][2048], Wcat=[2048][2048]/expert
    gemm1_kernel<true, DIMK, 2 * INTERN><<<dim3(16, (2 * INTERN) / 256, NEXP), 512, 0, stream>>>(
        At, WcatE, H, counts, poff, 0);
    // shared GEMM1: A=[4096][2048], Wcat=[4096][2048]
    gemm1_kernel<false, DIMK, 2 * SINTER><<<dim3(T_TOK / 256, (2 * SINTER) / 256, 1), 512, 0, stream>>>(
        xbT, WcatS, Hs, nullptr, nullptr, T_TOK);

    // shared GEMM2: K=2048, 2-way K-split, atomic into zeroed out
    gemm2_kernel<true, SINTER><<<dim3(T_TOK / 256, DIMK / 256, 2), 512, 0, stream>>>(
        Hs, swdT, out, nullptr, nullptr, nullptr, nullptr, T_TOK);

    // wd transpose into aliased WcatE region, placed immediately before its consumer (L3-warm)
    trans_tiled_kernel<INTERN, DIMK><<<dim3(DIMK / 64, INTERN / 64, NEXP), 256, 0, stream>>>(wd, wdT);

    // expert GEMM2 (reversed order matches wdT write tail): K=1024, atomic with routing weights
    gemm2_kernel<false, INTERN><<<dim3(16, DIMK / 256, NEXP), 512, 0, stream>>>(
        H, wdT, out, counts, ids, poff, wgts, 0);
}

// Round 9
// 1295.260 us; speedup vs baseline: 2.1067x; 1.1035x over previous
//
#include <hip/hip_runtime.h>
#include <hip/hip_bf16.h>

typedef float f32x4 __attribute__((ext_vector_type(4)));
typedef __bf16 bf16x8 __attribute__((ext_vector_type(8)));
typedef unsigned short u16;

#define T_TOK 4096
#define DIMK 2048
#define INTERN 1024
#define NEXP 32
#define NTOPK 6
#define NGRP 8
#define NTOPG 4
#define SINTER 2048
#define MAXPADROWS 29184

// async global->LDS 16B
__device__ __forceinline__ void glds16(const void* g, void* l) {
    auto* gp = (const __attribute__((address_space(1))) int*)(g);
    auto* lp = (__attribute__((address_space(3))) int*)(l);
    __builtin_amdgcn_global_load_lds(gp, lp, 16, 0, 0);
}

// Chunked+swizzled layout for [Rows][K] bf16: row-chunks of 128, k-chunks of 64.
// In-chunk (16KB): off = row*64 + ((g ^ (row&7))<<3) + (k&7), g=(k>>3)&7.
__device__ __forceinline__ size_t toff(int row, int k, int K) {
    int g = (k >> 3) & 7;
    return (size_t)(row >> 7) * (size_t)(128 * K) + (size_t)(k >> 6) * 8192 +
           (size_t)((row & 127) * 64 + ((g ^ (row & 7)) << 3) + (k & 7));
}

// ---------------- cast x fp32 -> bf16 chunked ----------------
__global__ __launch_bounds__(256) void cast_x_tiled_kernel(const float* __restrict__ in, u16* __restrict__ out) {
    int gi = (blockIdx.x * 256 + threadIdx.x) * 8;
    int row = gi >> 11, k = gi & 2047;
    const float4* p = reinterpret_cast<const float4*>(in + gi);
    float4 a = p[0], b = p[1];
    bf16x8 v;
    v[0] = (__bf16)a.x; v[1] = (__bf16)a.y; v[2] = (__bf16)a.z; v[3] = (__bf16)a.w;
    v[4] = (__bf16)b.x; v[5] = (__bf16)b.y; v[6] = (__bf16)b.z; v[7] = (__bf16)b.w;
    *reinterpret_cast<bf16x8*>(out + toff(row, k, DIMK)) = v;
}

// ---------------- single transpose: fp32 [KD][JD] -> bf16 chunked [JD][KD] ----------------
template <int KD, int JD>
__global__ __launch_bounds__(256) void trans_tiled_kernel(const float* __restrict__ in, u16* __restrict__ out) {
    __shared__ float tile[64 * 65];
    const int t = threadIdx.x;
    const float* ib = in + (size_t)blockIdx.z * KD * JD;
    u16* ob = out + (size_t)blockIdx.z * KD * JD;
    const int j0 = blockIdx.x * 64, k0 = blockIdx.y * 64;
    {
        const int c4 = (t & 15) * 4;
#pragma unroll
        for (int i = 0; i < 4; ++i) {
            const int r = (t >> 4) + i * 16;
            float4 v = *reinterpret_cast<const float4*>(&ib[(size_t)(k0 + r) * JD + j0 + c4]);
            tile[r * 65 + c4 + 0] = v.x;
            tile[r * 65 + c4 + 1] = v.y;
            tile[r * 65 + c4 + 2] = v.z;
            tile[r * 65 + c4 + 3] = v.w;
        }
    }
    __syncthreads();
    {
        const int jl = t >> 2, kh = (t & 3) * 16;
        const int n = j0 + jl;
        bf16x8 v0, v1;
#pragma unroll
        for (int j = 0; j < 8; ++j) v0[j] = (__bf16)tile[(kh + j) * 65 + jl];
#pragma unroll
        for (int j = 0; j < 8; ++j) v1[j] = (__bf16)tile[(kh + 8 + j) * 65 + jl];
        *reinterpret_cast<bf16x8*>(ob + toff(n, k0 + kh, KD)) = v0;
        *reinterpret_cast<bf16x8*>(ob + toff(n, k0 + kh + 8, KD)) = v1;
    }
}

// ---------------- cat transpose: wg,wu [KD][JD] -> Wcat chunked [2*JD][KD] ----------------
template <int KD, int JD>
__global__ __launch_bounds__(256) void cat_trans_kernel(const float* __restrict__ g0, const float* __restrict__ u0,
                                                        u16* __restrict__ out) {
    __shared__ float tile[64 * 65];
    const int t = threadIdx.x;
    const size_t so = (size_t)blockIdx.z * KD * JD;
    u16* ob = out + (size_t)blockIdx.z * (2 * (size_t)KD * JD);
    const int j0 = blockIdx.x * 32, k0 = blockIdx.y * 64;
    const int kl = t >> 2, jf = (t & 3) * 4;
#pragma unroll
    for (int s = 0; s < 2; ++s) {
        const float* src = (s ? u0 : g0) + so;
#pragma unroll
        for (int rep = 0; rep < 2; ++rep) {
            int jb = jf + rep * 16;
            float4 v = *reinterpret_cast<const float4*>(&src[(size_t)(k0 + kl) * JD + j0 + jb]);
            int nl = ((jb >> 4) << 5) + s * 16 + (jb & 15);
            tile[kl * 65 + nl + 0] = v.x;
            tile[kl * 65 + nl + 1] = v.y;
            tile[kl * 65 + nl + 2] = v.z;
            tile[kl * 65 + nl + 3] = v.w;
        }
    }
    __syncthreads();
    {
        const int nl = t >> 2, kh = (t & 3) * 16;
        const int n = 2 * j0 + nl;
        bf16x8 v0, v1;
#pragma unroll
        for (int j = 0; j < 8; ++j) v0[j] = (__bf16)tile[(kh + j) * 65 + nl];
#pragma unroll
        for (int j = 0; j < 8; ++j) v1[j] = (__bf16)tile[(kh + 8 + j) * 65 + nl];
        *reinterpret_cast<bf16x8*>(ob + toff(n, k0 + kh, KD)) = v0;
        *reinterpret_cast<bf16x8*>(ob + toff(n, k0 + kh + 8, KD)) = v1;
    }
}

// ---------------- gate: also emits per-token (expert,slot) packs + weights ----------------
__global__ __launch_bounds__(64) void gate_kernel(const float* __restrict__ x, const float* __restrict__ gw,
                                                  int* __restrict__ counts, int* __restrict__ ids,
                                                  int* __restrict__ tok2row, float* __restrict__ wtok) {
    const int t = blockIdx.x;
    const int lane = threadIdx.x;
    __shared__ float logits[NEXP];
    const float4* xr = reinterpret_cast<const float4*>(x + (size_t)t * DIMK);
    for (int e = 0; e < NEXP; ++e) {
        const float4* gr = reinterpret_cast<const float4*>(gw + (size_t)e * DIMK);
        float acc = 0.f;
#pragma unroll
        for (int i = 0; i < DIMK / 4 / 64; ++i) {
            float4 xv = xr[lane + i * 64];
            float4 gv = gr[lane + i * 64];
            acc += xv.x * gv.x + xv.y * gv.y + xv.z * gv.z + xv.w * gv.w;
        }
#pragma unroll
        for (int s = 32; s; s >>= 1) acc += __shfl_xor(acc, s);
        if (lane == 0) logits[e] = acc;
    }
    if (lane != 0) return;
    float sc[NEXP];
#pragma unroll
    for (int e = 0; e < NEXP; ++e) sc[e] = logits[e];
    float mx = sc[0];
#pragma unroll
    for (int e = 1; e < NEXP; ++e) mx = fmaxf(mx, sc[e]);
    float ssum = 0.f;
#pragma unroll
    for (int e = 0; e < NEXP; ++e) { sc[e] = __expf(sc[e] - mx); ssum += sc[e]; }
    const float inv = 1.f / ssum;
    float gsc[NGRP];
#pragma unroll
    for (int g = 0; g < NGRP; ++g) {
        float m2 = sc[g * 4];
#pragma unroll
        for (int j = 1; j < 4; ++j) m2 = fmaxf(m2, sc[g * 4 + j]);
        gsc[g] = m2;
    }
    int gsel = 0;
    for (int r = 0; r < NTOPG; ++r) {
        float bv = -1.f; int bi = 0;
#pragma unroll
        for (int g = 0; g < NGRP; ++g) {
            bool c = (((gsel >> g) & 1) == 0) && (gsc[g] > bv);
            bv = c ? gsc[g] : bv; bi = c ? g : bi;
        }
        gsel |= (1 << bi);
    }
    float msk[NEXP];
#pragma unroll
    for (int e = 0; e < NEXP; ++e) msk[e] = ((gsel >> (e >> 2)) & 1) ? sc[e] : -1.f;
    for (int r = 0; r < NTOPK; ++r) {
        float bv = -3.f; int bi = 0;
#pragma unroll
        for (int e = 0; e < NEXP; ++e) {
            bool c = msk[e] > bv;
            bv = c ? msk[e] : bv; bi = c ? e : bi;
        }
#pragma unroll
        for (int e = 0; e < NEXP; ++e) if (e == bi) msk[e] = -2.f;
        float w = bv * inv;
        int slot = atomicAdd(&counts[bi], 1);
        ids[bi * T_TOK + slot] = t;
        tok2row[t * NTOPK + r] = (bi << 12) | slot;   // slot < 4096 fits 12 bits
        wtok[t * NTOPK + r] = w;
    }
}

// ---------------- scan: 128-padded exclusive offsets ----------------
__global__ void scan_kernel(const int* __restrict__ counts, int* __restrict__ poff) {
    if (threadIdx.x == 0) {
        int o = 0;
        for (int e = 0; e < NEXP; ++e) { poff[e] = o; o += (counts[e] + 127) & ~127; }
    }
}

// ---------------- gather: x fp32 rows -> per-expert padded chunked bf16 A ----------------
__global__ __launch_bounds__(256) void gather_a_kernel(const float* __restrict__ x, const int* __restrict__ ids,
                                                       const int* __restrict__ counts, const int* __restrict__ poff,
                                                       u16* __restrict__ At) {
    const int e = blockIdx.y, bm = blockIdx.x;
    const int M = counts[e];
    if (bm * 128 >= M) return;
    const int t = threadIdx.x;
    const int r = t >> 1, h = t & 1;
    const int lr = bm * 128 + r;
    const int cr = lr < M ? lr : M - 1;
    const int tok = ids[e * T_TOK + cr];
    const float* src = x + (size_t)tok * DIMK;
    u16* dst = At + ((size_t)poff[e] + (size_t)bm * 128) * DIMK + r * 64;
    const int rx = r & 7;
#pragma unroll 2
    for (int kc = 0; kc < DIMK / 64; ++kc) {
#pragma unroll
        for (int gi = 0; gi < 4; ++gi) {
            int g = h * 4 + gi;
            const float* s = src + kc * 64 + g * 8;
            float4 f0 = *reinterpret_cast<const float4*>(s);
            float4 f1 = *reinterpret_cast<const float4*>(s + 4);
            bf16x8 v;
            v[0] = (__bf16)f0.x; v[1] = (__bf16)f0.y; v[2] = (__bf16)f0.z; v[3] = (__bf16)f0.w;
            v[4] = (__bf16)f1.x; v[5] = (__bf16)f1.y; v[6] = (__bf16)f1.z; v[7] = (__bf16)f1.w;
            *reinterpret_cast<bf16x8*>(dst + (size_t)kc * 8192 + ((g ^ rx) << 3)) = v;
        }
    }
}

// ================= 256x256 / BK=64 / 8-wave GEMM =================
// Pipeline per K-tile: vmcnt(8)->barrier1 -> dsread+4 MFMA quadrants -> barrier2 -> STGALL(t+2,buf)
// barrier2 closes the WAR hazard (all waves done reading buf before its DMA overwrite is issued).
// GEMM1: H = silu(A*Wcat_g) * (A*Wcat_u), Wcat 16-col interleaved. NN = Wcat rows.
template <bool GATHER, int KK, int NN>
__global__ __launch_bounds__(512, 2) void gemm1_kernel(
    const u16* __restrict__ Abase, const u16* __restrict__ Bcat, u16* __restrict__ Hout,
    const int* __restrict__ counts, const int* __restrict__ poff, int Mshared) {
    __shared__ u16 Alds[4 * 8192];  // [buf][half][8192]
    __shared__ u16 Blds[4 * 8192];

    int bm, bn, e;
    if (GATHER) {
        // XCD-pinned (e & 7 == lin & 7), bm-inner; reversed expert order for L3 warmth
        int lin = blockIdx.x + 16 * (blockIdx.y + 8 * blockIdx.z);   // grid (16,8,32)
        e = (NEXP - 1) - (((lin >> 10) << 3) | (lin & 7));
        int j = (lin >> 3) & 127;
        bn = j >> 4; bm = j & 15;
    } else {
        int lin = blockIdx.x + 16 * blockIdx.y;                      // grid (16,16)
        int swz = (lin & 7) * 32 + (lin >> 3);
        bm = swz & 15; bn = swz >> 4; e = 0;
    }

    int M, Mpad, hbase;
    const u16 *a0, *b0;
    if (GATHER) {
        M = counts[e];
        if (bm * 256 >= M) return;
        Mpad = (M + 127) & ~127;
        hbase = poff[e];
        a0 = Abase + (size_t)poff[e] * KK;
        b0 = Bcat + (size_t)e * NN * KK;
    } else {
        M = Mshared; Mpad = Mshared; hbase = 0; a0 = Abase; b0 = Bcat;
        if (bm * 256 >= M) return;
    }
    const int tid = threadIdx.x, lane = tid & 63, wv = tid >> 6;
    const int wr = wv >> 2, wc = wv & 3;
    const int l15 = lane & 15, lk = lane >> 4;

    const u16* aCh[2] = { a0 + (size_t)(2 * bm + 0) * (128 * KK), a0 + (size_t)(2 * bm + 1) * (128 * KK) };
    const u16* bCh[2] = { b0 + (size_t)(2 * bn + 0) * (128 * KK), b0 + (size_t)(2 * bn + 1) * (128 * KK) };
    const int t8 = tid * 8;

    f32x4 acc[8][4];
#pragma unroll
    for (int m = 0; m < 8; ++m)
#pragma unroll
        for (int n = 0; n < 4; ++n) acc[m][n] = {0.f, 0.f, 0.f, 0.f};

    auto STGALL = [&](int kt, int buf) {
        glds16(aCh[0] + (size_t)kt * 8192 + t8, &Alds[(buf * 2 + 0) * 8192 + t8]);
        glds16(aCh[0] + (size_t)kt * 8192 + 4096 + t8, &Alds[(buf * 2 + 0) * 8192 + 4096 + t8]);
        glds16(aCh[1] + (size_t)kt * 8192 + t8, &Alds[(buf * 2 + 1) * 8192 + t8]);
        glds16(aCh[1] + (size_t)kt * 8192 + 4096 + t8, &Alds[(buf * 2 + 1) * 8192 + 4096 + t8]);
        glds16(bCh[0] + (size_t)kt * 8192 + t8, &Blds[(buf * 2 + 0) * 8192 + t8]);
        glds16(bCh[0] + (size_t)kt * 8192 + 4096 + t8, &Blds[(buf * 2 + 0) * 8192 + 4096 + t8]);
        glds16(bCh[1] + (size_t)kt * 8192 + t8, &Blds[(buf * 2 + 1) * 8192 + t8]);
        glds16(bCh[1] + (size_t)kt * 8192 + 4096 + t8, &Blds[(buf * 2 + 1) * 8192 + 4096 + t8]);
    };
    auto DSRA = [&](int buf, int mq, bf16x8 a[4][2]) {
#pragma unroll
        for (int mi = 0; mi < 4; ++mi)
#pragma unroll
            for (int ki = 0; ki < 2; ++ki) {
                int rl = mq * 64 + mi * 16 + l15;
                int g = ki * 4 + lk;
                a[mi][ki] = *reinterpret_cast<const bf16x8*>(&Alds[(buf * 2 + wr) * 8192 + rl * 64 + ((g ^ (rl & 7)) << 3)]);
            }
    };
    auto DSRB = [&](int buf, int nh, bf16x8 b[2][2]) {
#pragma unroll
        for (int ni = 0; ni < 2; ++ni)
#pragma unroll
            for (int ki = 0; ki < 2; ++ki) {
                int rc = (wc & 1) * 64 + nh * 32 + ni * 16 + l15;
                int g = ki * 4 + lk;
                b[ni][ki] = *reinterpret_cast<const bf16x8*>(&Blds[(buf * 2 + (wc >> 1)) * 8192 + rc * 64 + ((g ^ (rc & 7)) << 3)]);
            }
    };

    bf16x8 a[4][2], br0[2][2], br1[2][2];
    constexpr int NT = KK / 64;
    STGALL(0, 0);
    STGALL(1, 1);

#pragma unroll 1
    for (int t = 0; t < NT; ++t) {
        const int buf = t & 1;
        if (t + 1 < NT) {
            asm volatile("s_waitcnt vmcnt(8)" ::: "memory");
        } else {
            asm volatile("s_waitcnt vmcnt(0)" ::: "memory");
        }
        __builtin_amdgcn_s_barrier();          // barrier1: tile t landed everywhere
        __builtin_amdgcn_sched_barrier(0);
        DSRA(buf, 0, a);
        DSRB(buf, 0, br0);
        __builtin_amdgcn_s_setprio(1);
#pragma unroll
        for (int ki = 0; ki < 2; ++ki)
#pragma unroll
            for (int mi = 0; mi < 4; ++mi)
#pragma unroll
                for (int ni = 0; ni < 2; ++ni)
                    acc[mi][ni] = __builtin_amdgcn_mfma_f32_16x16x32_bf16(a[mi][ki], br0[ni][ki], acc[mi][ni], 0, 0, 0);
        __builtin_amdgcn_s_setprio(0);
        DSRB(buf, 1, br1);
        __builtin_amdgcn_s_setprio(1);
#pragma unroll
        for (int ki = 0; ki < 2; ++ki)
#pragma unroll
            for (int mi = 0; mi < 4; ++mi)
#pragma unroll
                for (int ni = 0; ni < 2; ++ni)
                    acc[mi][2 + ni] = __builtin_amdgcn_mfma_f32_16x16x32_bf16(a[mi][ki], br1[ni][ki], acc[mi][2 + ni], 0, 0, 0);
        __builtin_amdgcn_s_setprio(0);
        DSRA(buf, 1, a);
        __builtin_amdgcn_s_setprio(1);
#pragma unroll
        for (int ki = 0; ki < 2; ++ki)
#pragma unroll
            for (int mi = 0; mi < 4; ++mi)
#pragma unroll
                for (int ni = 0; ni < 2; ++ni) {
                    acc[4 + mi][2 + ni] = __builtin_amdgcn_mfma_f32_16x16x32_bf16(a[mi][ki], br1[ni][ki], acc[4 + mi][2 + ni], 0, 0, 0);
                    acc[4 + mi][ni] = __builtin_amdgcn_mfma_f32_16x16x32_bf16(a[mi][ki], br0[ni][ki], acc[4 + mi][ni], 0, 0, 0);
                }
        __builtin_amdgcn_s_setprio(0);
        __builtin_amdgcn_sched_barrier(0);
        __builtin_amdgcn_s_barrier();          // barrier2: all reads of buf complete
        __builtin_amdgcn_sched_barrier(0);
        if (t + 2 < NT) STGALL(t + 2, buf);    // safe overwrite of buf
    }

    // epilogue: h = silu(g)*u -> H chunked
    constexpr int HK = NN / 2;
#pragma unroll
    for (int mI = 0; mI < 8; ++mI) {
#pragma unroll
        for (int r = 0; r < 4; ++r) {
            int rowt = wr * 128 + (mI >> 2) * 64 + (mI & 3) * 16 + lk * 4 + r;
            int grow = bm * 256 + rowt;
            if (grow < Mpad) {
#pragma unroll
                for (int nh = 0; nh < 2; ++nh) {
                    float gg = acc[mI][nh * 2 + 0][r];
                    float uu = acc[mI][nh * 2 + 1][r];
                    float h = gg / (1.f + __expf(-gg)) * uu;
                    int ic = bn * 128 + wc * 32 + nh * 16 + l15;
                    __bf16 hb = (__bf16)h;
                    Hout[toff(hbase + grow, ic, HK)] = __builtin_bit_cast(u16, hb);
                }
            }
        }
    }
}

// GEMM2: Y = H * Wd -> plain bf16 stores into Yout rows (no atomics). NN=2048.
template <bool SHARED, int KK>
__global__ __launch_bounds__(512, 2) void gemm2_kernel(
    const u16* __restrict__ Hbase, const u16* __restrict__ Bd, u16* __restrict__ Yout,
    const int* __restrict__ counts, const int* __restrict__ poff, int Mshared) {
    __shared__ u16 Alds[4 * 8192];
    __shared__ u16 Blds[4 * 8192];

    constexpr int NT = SHARED ? (KK / 128) : (KK / 64);
    int bm, bn, e = 0, kt0 = 0, rowbase = 0;
    if (SHARED) {
        int lin = blockIdx.x + 16 * (blockIdx.y + 8 * blockIdx.z);   // grid (16,8,2)
        int swz = (lin & 7) * 32 + (lin >> 3);
        bm = swz & 15; bn = (swz >> 4) & 7;
        int z = swz >> 7;
        kt0 = z * NT; rowbase = z * T_TOK;
    } else {
        int lin = blockIdx.x + 16 * (blockIdx.y + 8 * blockIdx.z);   // grid (16,8,32)
        e = (NEXP - 1) - (((lin >> 10) << 3) | (lin & 7));
        int j = (lin >> 3) & 127;
        bn = j >> 4; bm = j & 15;
    }

    int M;
    const u16 *a0, *b0;
    if (SHARED) {
        M = Mshared; a0 = Hbase; b0 = Bd;
    } else {
        M = counts[e];
        if (bm * 256 >= M) return;
        rowbase = poff[e];
        a0 = Hbase + (size_t)poff[e] * KK;
        b0 = Bd + (size_t)e * 2048 * KK;
    }
    const int tid = threadIdx.x, lane = tid & 63, wv = tid >> 6;
    const int wr = wv >> 2, wc = wv & 3;
    const int l15 = lane & 15, lk = lane >> 4;

    const u16* aCh[2] = { a0 + (size_t)(2 * bm + 0) * (128 * KK) + (size_t)kt0 * 8192,
                          a0 + (size_t)(2 * bm + 1) * (128 * KK) + (size_t)kt0 * 8192 };
    const u16* bCh[2] = { b0 + (size_t)(2 * bn + 0) * (128 * KK) + (size_t)kt0 * 8192,
                          b0 + (size_t)(2 * bn + 1) * (128 * KK) + (size_t)kt0 * 8192 };
    const int t8 = tid * 8;

    f32x4 acc[8][4];
#pragma unroll
    for (int m = 0; m < 8; ++m)
#pragma unroll
        for (int n = 0; n < 4; ++n) acc[m][n] = {0.f, 0.f, 0.f, 0.f};

    auto STGALL = [&](int kt, int buf) {
        glds16(aCh[0] + (size_t)kt * 8192 + t8, &Alds[(buf * 2 + 0) * 8192 + t8]);
        glds16(aCh[0] + (size_t)kt * 8192 + 4096 + t8, &Alds[(buf * 2 + 0) * 8192 + 4096 + t8]);
        glds16(aCh[1] + (size_t)kt * 8192 + t8, &Alds[(buf * 2 + 1) * 8192 + t8]);
        glds16(aCh[1] + (size_t)kt * 8192 + 4096 + t8, &Alds[(buf * 2 + 1) * 8192 + 4096 + t8]);
        glds16(bCh[0] + (size_t)kt * 8192 + t8, &Blds[(buf * 2 + 0) * 8192 + t8]);
        glds16(bCh[0] + (size_t)kt * 8192 + 4096 + t8, &Blds[(buf * 2 + 0) * 8192 + 4096 + t8]);
        glds16(bCh[1] + (size_t)kt * 8192 + t8, &Blds[(buf * 2 + 1) * 8192 + t8]);
        glds16(bCh[1] + (size_t)kt * 8192 + 4096 + t8, &Blds[(buf * 2 + 1) * 8192 + 4096 + t8]);
    };
    auto DSRA = [&](int buf, int mq, bf16x8 a[4][2]) {
#pragma unroll
        for (int mi = 0; mi < 4; ++mi)
#pragma unroll
            for (int ki = 0; ki < 2; ++ki) {
                int rl = mq * 64 + mi * 16 + l15;
                int g = ki * 4 + lk;
                a[mi][ki] = *reinterpret_cast<const bf16x8*>(&Alds[(buf * 2 + wr) * 8192 + rl * 64 + ((g ^ (rl & 7)) << 3)]);
            }
    };
    auto DSRB = [&](int buf, int nh, bf16x8 b[2][2]) {
#pragma unroll
        for (int ni = 0; ni < 2; ++ni)
#pragma unroll
            for (int ki = 0; ki < 2; ++ki) {
                int rc = (wc & 1) * 64 + nh * 32 + ni * 16 + l15;
                int g = ki * 4 + lk;
                b[ni][ki] = *reinterpret_cast<const bf16x8*>(&Blds[(buf * 2 + (wc >> 1)) * 8192 + rc * 64 + ((g ^ (rc & 7)) << 3)]);
            }
    };

    bf16x8 a[4][2], br0[2][2], br1[2][2];
    STGALL(0, 0);
    STGALL(1, 1);

#pragma unroll 1
    for (int t = 0; t < NT; ++t) {
        const int buf = t & 1;
        if (t + 1 < NT) {
            asm volatile("s_waitcnt vmcnt(8)" ::: "memory");
        } else {
            asm volatile("s_waitcnt vmcnt(0)" ::: "memory");
        }
        __builtin_amdgcn_s_barrier();
        __builtin_amdgcn_sched_barrier(0);
        DSRA(buf, 0, a);
        DSRB(buf, 0, br0);
        __builtin_amdgcn_s_setprio(1);
#pragma unroll
        for (int ki = 0; ki < 2; ++ki)
#pragma unroll
            for (int mi = 0; mi < 4; ++mi)
#pragma unroll
                for (int ni = 0; ni < 2; ++ni)
                    acc[mi][ni] = __builtin_amdgcn_mfma_f32_16x16x32_bf16(a[mi][ki], br0[ni][ki], acc[mi][ni], 0, 0, 0);
        __builtin_amdgcn_s_setprio(0);
        DSRB(buf, 1, br1);
        __builtin_amdgcn_s_setprio(1);
#pragma unroll
        for (int ki = 0; ki < 2; ++ki)
#pragma unroll
            for (int mi = 0; mi < 4; ++mi)
#pragma unroll
                for (int ni = 0; ni < 2; ++ni)
                    acc[mi][2 + ni] = __builtin_amdgcn_mfma_f32_16x16x32_bf16(a[mi][ki], br1[ni][ki], acc[mi][2 + ni], 0, 0, 0);
        __builtin_amdgcn_s_setprio(0);
        DSRA(buf, 1, a);
        __builtin_amdgcn_s_setprio(1);
#pragma unroll
        for (int ki = 0; ki < 2; ++ki)
#pragma unroll
            for (int mi = 0; mi < 4; ++mi)
#pragma unroll
                for (int ni = 0; ni < 2; ++ni) {
                    acc[4 + mi][2 + ni] = __builtin_amdgcn_mfma_f32_16x16x32_bf16(a[mi][ki], br1[ni][ki], acc[4 + mi][2 + ni], 0, 0, 0);
                    acc[4 + mi][ni] = __builtin_amdgcn_mfma_f32_16x16x32_bf16(a[mi][ki], br0[ni][ki], acc[4 + mi][ni], 0, 0, 0);
                }
        __builtin_amdgcn_s_setprio(0);
        __builtin_amdgcn_sched_barrier(0);
        __builtin_amdgcn_s_barrier();
        __builtin_amdgcn_sched_barrier(0);
        if (t + 2 < NT) STGALL(t + 2, buf);
    }

#pragma unroll
    for (int mI = 0; mI < 8; ++mI) {
#pragma unroll
        for (int r = 0; r < 4; ++r) {
            int rowt = wr * 128 + (mI >> 2) * 64 + (mI & 3) * 16 + lk * 4 + r;
            int grow = bm * 256 + rowt;
            if (grow < M) {
                u16* yr = Yout + (size_t)(rowbase + grow) * 2048;
#pragma unroll
                for (int nI = 0; nI < 4; ++nI) {
                    int col = bn * 256 + wc * 64 + (nI >> 1) * 32 + (nI & 1) * 16 + l15;
                    __bf16 yb = (__bf16)acc[mI][nI][r];
                    yr[col] = __builtin_bit_cast(u16, yb);
                }
            }
        }
    }
}

// ---------------- combine: out[t] = Yss0[t] + Yss1[t] + sum_r w_r * Ye[row_r] ----------------
__global__ __launch_bounds__(256) void combine_kernel(const u16* __restrict__ Yss, const u16* __restrict__ Ye,
                                                      const int* __restrict__ tok2row, const float* __restrict__ wtok,
                                                      const int* __restrict__ poff, float* __restrict__ out) {
    const int t = blockIdx.x;
    const int c = threadIdx.x * 8;
    bf16x8 v0 = *reinterpret_cast<const bf16x8*>(Yss + (size_t)t * 2048 + c);
    bf16x8 v1 = *reinterpret_cast<const bf16x8*>(Yss + (size_t)(T_TOK + t) * 2048 + c);
    float acc[8];
#pragma unroll
    for (int j = 0; j < 8; ++j) acc[j] = (float)v0[j] + (float)v1[j];
#pragma unroll
    for (int r = 0; r < NTOPK; ++r) {
        int pk = tok2row[t * NTOPK + r];
        int e = pk >> 12, sl = pk & 4095;
        int row = poff[e] + sl;
        float w = wtok[t * NTOPK + r];
        bf16x8 v = *reinterpret_cast<const bf16x8*>(Ye + (size_t)row * 2048 + c);
#pragma unroll
        for (int j = 0; j < 8; ++j) acc[j] += w * (float)v[j];
    }
    float4 o0 = {acc[0], acc[1], acc[2], acc[3]};
    float4 o1 = {acc[4], acc[5], acc[6], acc[7]};
    float4* po = reinterpret_cast<float4*>(out + (size_t)t * 2048 + c);
    po[0] = o0; po[1] = o1;
}

extern "C" void kernel_launch(void* const* d_in, const int* in_sizes, int n_in,
                              void* d_out, int out_size, void* d_ws, size_t ws_size,
                              hipStream_t stream) {
    const float* x = (const float*)d_in[0];
    const float* gate_w = (const float*)d_in[1];
    const float* wg = (const float*)d_in[2];
    const float* wu = (const float*)d_in[3];
    const float* wd = (const float*)d_in[4];
    const float* swg = (const float*)d_in[5];
    const float* swu = (const float*)d_in[6];
    const float* swd = (const float*)d_in[7];
    float* out = (float*)d_out;

    char* ws = (char*)d_ws;
    size_t off = 0;
    auto alloc = [&](size_t bytes) {
        void* p = ws + off;
        off = (off + bytes + 255) & ~(size_t)255;
        return p;
    };
    u16* xbT = (u16*)alloc((size_t)T_TOK * DIMK * 2);                  // 16.8 MB
    u16* At = (u16*)alloc((size_t)MAXPADROWS * DIMK * 2);              // 119.6 MB
    u16* H = (u16*)alloc((size_t)MAXPADROWS * INTERN * 2);             // 59.8 MB
    u16* Yss = (u16*)alloc((size_t)2 * T_TOK * 2048 * 2);              // 33.6 MB
    int* ids = (int*)alloc((size_t)NEXP * T_TOK * 4);
    int* tok2row = (int*)alloc((size_t)T_TOK * NTOPK * 4);
    float* wtok = (float*)alloc((size_t)T_TOK * NTOPK * 4);
    int* counts = (int*)alloc(NEXP * 4);
    int* poff = (int*)alloc(NEXP * 4);
    u16* WcatS = (u16*)alloc((size_t)(2 * SINTER) * DIMK * 2);         // 16.8 MB
    u16* swdT = (u16*)alloc((size_t)DIMK * SINTER * 2);                // 8.4 MB
    u16* WcatE = (u16*)alloc((size_t)NEXP * (2 * INTERN) * DIMK * 2);  // 268.4 MB
    u16* wdT = WcatE;  // alias: wd transpose after GEMM1s consumed WcatE (stream-ordered)
    u16* Hs = At;      // alias: shared-H written after eGEMM1 consumed At (stream-ordered)
    u16* Ye = At;      // alias: Ye written by eGEMM2 after sGEMM2 consumed Hs (stream-ordered)

    hipMemsetAsync(counts, 0, NEXP * 4, stream);
    cast_x_tiled_kernel<<<(T_TOK * DIMK) / (256 * 8), 256, 0, stream>>>(x, xbT);
    gate_kernel<<<T_TOK, 64, 0, stream>>>(x, gate_w, counts, ids, tok2row, wtok);
    scan_kernel<<<1, 64, 0, stream>>>(counts, poff);
    gather_a_kernel<<<dim3(32, NEXP), 256, 0, stream>>>(x, ids, counts, poff, At);

    // weight reshapes
    cat_trans_kernel<DIMK, SINTER><<<dim3(SINTER / 32, DIMK / 64, 1), 256, 0, stream>>>(swg, swu, WcatS);
    cat_trans_kernel<DIMK, INTERN><<<dim3(INTERN / 32, DIMK / 64, NEXP), 256, 0, stream>>>(wg, wu, WcatE);
    trans_tiled_kernel<SINTER, DIMK><<<dim3(DIMK / 64, SINTER / 64, 1), 256, 0, stream>>>(swd, swdT);

    // expert GEMM1: A=[Mpad][2048], Wcat=[2048][2048] per expert -> H
    gemm1_kernel<true, DIMK, 2 * INTERN><<<dim3(16, 8, NEXP), 512, 0, stream>>>(
        At, WcatE, H, counts, poff, 0);
    // shared GEMM1: A=[4096][2048], Wcat=[4096][2048] -> Hs (aliases At)
    gemm1_kernel<false, DIMK, 2 * SINTER><<<dim3(16, 16, 1), 512, 0, stream>>>(
        xbT, WcatS, Hs, nullptr, nullptr, T_TOK);

    // shared GEMM2: K=2048 split 2 ways -> Yss slices (bf16 plain stores)
    gemm2_kernel<true, SINTER><<<dim3(16, 8, 2), 512, 0, stream>>>(
        Hs, swdT, Yss, nullptr, nullptr, T_TOK);

    // wd transpose into aliased WcatE region (L3-warm at use)
    trans_tiled_kernel<INTERN, DIMK><<<dim3(DIMK / 64, INTERN / 64, NEXP), 256, 0, stream>>>(wd, wdT);

    // expert GEMM2: K=1024 -> Ye rows (bf16 plain stores; Ye aliases At, Hs consumed)
    gemm2_kernel<false, INTERN><<<dim3(16, 8, NEXP), 512, 0, stream>>>(
        H, wdT, Ye, counts, poff, 0);

    // final combine -> out (full overwrite; no memset needed)
    combine_kernel<<<T_TOK, 256, 0, stream>>>(Yss, Ye, tok2row, wtok, poff, out);
}